// Round 5
// baseline (2407.753 us; speedup 1.0000x reference)
//
#include <hip/hip_runtime.h>

#define N_NODES  1000000
#define N_EDGES  32000000
#define N_GRAPHS 1024
#define N_LAYERS 8
#define OUT_COLS (N_LAYERS + 1)

#define BKT_SHIFT 11
#define BKT_NODES 2048
#define NBKT      489            // ceil(1e6 / 2048); last bucket has 576 nodes
#define NBKT_PAD  512
#define KSPLIT    4              // blocks per bucket in edge pass
#define SCAT_BLOCKS 256
#define SCAT_THREADS 1024
#define SCAT_CHUNK  (N_EDGES / SCAT_BLOCKS)   // 125000 exactly

// ---------------------------------------------------------------------------
// Wave-segmented accumulation of per-graph sums (graph_ids sorted, so most
// 64-lane waves are gid-uniform -> one atomic per wave). Call sites guarantee
// waves are fully active or fully inactive.
// ---------------------------------------------------------------------------
__device__ inline void seg_accum(int gid, float val, float* __restrict__ out, int col) {
    int g0 = __shfl(gid, 0);
    if (__all(gid == g0)) {
        #pragma unroll
        for (int off = 32; off > 0; off >>= 1)
            val += __shfl_down(val, off);
        if ((threadIdx.x & 63) == 0)
            atomicAdd(&out[g0 * OUT_COLS + col], val);
    } else {
        atomicAdd(&out[gid * OUT_COLS + col], val);
    }
}

// ------------------------- preprocessing: binning --------------------------

// P1: global bucket histogram (LDS-privatized, int4-vectorized)
__global__ void count_kernel(const int4* __restrict__ dst4, unsigned* __restrict__ g_count) {
    __shared__ unsigned hist[NBKT_PAD];
    for (int j = threadIdx.x; j < NBKT_PAD; j += blockDim.x) hist[j] = 0u;
    __syncthreads();
    int stride = gridDim.x * blockDim.x;
    for (int t = blockIdx.x * blockDim.x + threadIdx.x; t < N_EDGES / 4; t += stride) {
        int4 d = dst4[t];
        atomicAdd(&hist[((unsigned)d.x) >> BKT_SHIFT], 1u);
        atomicAdd(&hist[((unsigned)d.y) >> BKT_SHIFT], 1u);
        atomicAdd(&hist[((unsigned)d.z) >> BKT_SHIFT], 1u);
        atomicAdd(&hist[((unsigned)d.w) >> BKT_SHIFT], 1u);
    }
    __syncthreads();
    for (int j = threadIdx.x; j < NBKT_PAD; j += blockDim.x)
        if (hist[j]) atomicAdd(&g_count[j], hist[j]);
}

// P2: exclusive scan of padded bucket counts (single block of NBKT_PAD threads)
__global__ void scan_kernel(const unsigned* __restrict__ g_count,
                            unsigned* __restrict__ g_base,
                            unsigned* __restrict__ g_cursor) {
    __shared__ unsigned s[NBKT_PAD];
    int t = threadIdx.x;
    unsigned c = g_count[t];
    s[t] = c;
    __syncthreads();
    for (int off = 1; off < NBKT_PAD; off <<= 1) {
        unsigned v = (t >= off) ? s[t - off] : 0u;
        __syncthreads();
        s[t] += v;
        __syncthreads();
    }
    unsigned incl = s[t];
    g_base[t]   = incl - c;
    g_cursor[t] = incl - c;
    if (t == NBKT_PAD - 1) g_base[NBKT_PAD] = incl;
}

// P3: scatter edges into bucket-contiguous u64 records.
// rec = (src | dst_low11 << 20) << 32 | f32bits(weight)
// 256 blocks x 489 buckets -> ~2MB active line set per XCD: L2 merges the
// scattered 8B writes into full lines (no nontemporal stores).
__global__ void scatter_kernel(const int* __restrict__ src,
                               const int* __restrict__ dst,
                               const float* __restrict__ ew,
                               unsigned* __restrict__ g_cursor,
                               unsigned long long* __restrict__ recs) {
    __shared__ unsigned lhist[NBKT_PAD];
    __shared__ unsigned lbase[NBKT_PAD];
    int e0 = blockIdx.x * SCAT_CHUNK;
    int e1 = e0 + SCAT_CHUNK;
    for (int j = threadIdx.x; j < NBKT_PAD; j += blockDim.x) lhist[j] = 0u;
    __syncthreads();
    for (int e = e0 + threadIdx.x; e < e1; e += blockDim.x)
        atomicAdd(&lhist[((unsigned)dst[e]) >> BKT_SHIFT], 1u);
    __syncthreads();
    for (int j = threadIdx.x; j < NBKT_PAD; j += blockDim.x) {
        unsigned c = lhist[j];
        lbase[j] = c ? atomicAdd(&g_cursor[j], c) : 0u;
    }
    __syncthreads();
    for (int j = threadIdx.x; j < NBKT_PAD; j += blockDim.x) lhist[j] = 0u;  // reuse as cursor
    __syncthreads();
    for (int e = e0 + threadIdx.x; e < e1; e += blockDim.x) {
        unsigned d = (unsigned)dst[e];
        unsigned b = d >> BKT_SHIFT;
        unsigned loc = atomicAdd(&lhist[b], 1u);
        unsigned pos = lbase[b] + loc;
        unsigned hi  = ((unsigned)src[e]) | ((d & (BKT_NODES - 1u)) << 20);
        recs[pos] = ((unsigned long long)hi << 32) | (unsigned)__float_as_uint(ew[e]);
    }
}

// ------------------------------ forward pass --------------------------------

// h0 = x; out[:,0] += per-graph sum of x
__global__ void init_kernel(const float* __restrict__ x,
                            const int* __restrict__ gids,
                            float* __restrict__ h0,
                            float* __restrict__ out) {
    int i = blockIdx.x * blockDim.x + threadIdx.x;
    if (i >= N_NODES) return;
    float v = x[i];
    h0[i] = v;
    seg_accum(gids[i], v, out, 0);
}

// Edge pass: KSPLIT blocks per bucket, each LDS-aggregates a quarter of the
// bucket's edges (unroll-4 pipeline: independent loads -> gathers -> LDS
// atomics), then writes its 2048-float partial coalesced.
__global__ __launch_bounds__(512) void edge_kernel(
        const unsigned long long* __restrict__ recs,
        const unsigned* __restrict__ g_base,
        const float* __restrict__ h_old,
        float* __restrict__ partials) {
    __shared__ float agg[BKT_NODES];
    int blk = blockIdx.x;
    int b   = blk >> 2;          // bucket
    int q   = blk & 3;           // quarter
    for (int j = threadIdx.x; j < BKT_NODES; j += 512) agg[j] = 0.0f;
    __syncthreads();
    int eb0 = (int)g_base[b];
    int len = (int)g_base[b + 1] - eb0;
    int qs  = eb0 + ((len * q) >> 2);
    int qe  = eb0 + ((len * (q + 1)) >> 2);

    int i = qs + threadIdx.x;
    for (; i + 3 * 512 < qe; i += 4 * 512) {
        unsigned long long r0 = __builtin_nontemporal_load(&recs[i]);
        unsigned long long r1 = __builtin_nontemporal_load(&recs[i + 512]);
        unsigned long long r2 = __builtin_nontemporal_load(&recs[i + 1024]);
        unsigned long long r3 = __builtin_nontemporal_load(&recs[i + 1536]);
        float h0v = h_old[(unsigned)(r0 >> 32) & 0xFFFFFu];
        float h1v = h_old[(unsigned)(r1 >> 32) & 0xFFFFFu];
        float h2v = h_old[(unsigned)(r2 >> 32) & 0xFFFFFu];
        float h3v = h_old[(unsigned)(r3 >> 32) & 0xFFFFFu];
        atomicAdd(&agg[(unsigned)(r0 >> 52)], h0v * __uint_as_float((unsigned)r0));
        atomicAdd(&agg[(unsigned)(r1 >> 52)], h1v * __uint_as_float((unsigned)r1));
        atomicAdd(&agg[(unsigned)(r2 >> 52)], h2v * __uint_as_float((unsigned)r2));
        atomicAdd(&agg[(unsigned)(r3 >> 52)], h3v * __uint_as_float((unsigned)r3));
    }
    for (; i < qe; i += 512) {
        unsigned long long r = __builtin_nontemporal_load(&recs[i]);
        float hv = h_old[(unsigned)(r >> 32) & 0xFFFFFu];
        atomicAdd(&agg[(unsigned)(r >> 52)], hv * __uint_as_float((unsigned)r));
    }
    __syncthreads();
    float* pout = partials + (size_t)blk * BKT_NODES;
    for (int j = threadIdx.x; j < BKT_NODES; j += 512)
        pout[j] = agg[j];
}

// Node pass: sum the KSPLIT partials, affine+relu, h write, per-graph sum.
__global__ void node_kernel(const float* __restrict__ partials,
                            const float* __restrict__ h_old,
                            float* __restrict__ h_new,
                            const int* __restrict__ gids,
                            const float* __restrict__ Wn,
                            const float* __restrict__ bn,
                            const float* __restrict__ Ws,
                            float* __restrict__ out,
                            int l) {
    int n = blockIdx.x * blockDim.x + threadIdx.x;
    if (n >= N_NODES) return;
    int b = n >> BKT_SHIFT;
    int j = n & (BKT_NODES - 1);
    const float* p = partials + (size_t)(b * KSPLIT) * BKT_NODES + j;
    float a = (p[0] + p[BKT_NODES]) + (p[2 * BKT_NODES] + p[3 * BKT_NODES]);
    float hn = fmaxf(fmaf(a, Wn[l], fmaf(h_old[n], Ws[l], bn[l])), 0.0f);
    h_new[n] = hn;
    seg_accum(gids[n], hn, out, l + 1);
}

// ------------------------- fallback (round-1 path) --------------------------

__global__ void fb_init_kernel(const float* __restrict__ x, const int* __restrict__ gids,
                               float* __restrict__ h, float* __restrict__ agg,
                               float* __restrict__ out) {
    int i = blockIdx.x * blockDim.x + threadIdx.x;
    if (i >= N_NODES) return;
    float v = x[i];
    h[i] = v; agg[i] = 0.0f;
    seg_accum(gids[i], v, out, 0);
}
__global__ void fb_edge_kernel(const int4* __restrict__ src4, const int4* __restrict__ dst4,
                               const float4* __restrict__ ew4, const float* __restrict__ h,
                               float* __restrict__ agg) {
    int t = blockIdx.x * blockDim.x + threadIdx.x;
    if (t >= N_EDGES / 4) return;
    int4 s = src4[t]; int4 d = dst4[t]; float4 w = ew4[t];
    atomicAdd(&agg[d.x], h[s.x] * w.x);
    atomicAdd(&agg[d.y], h[s.y] * w.y);
    atomicAdd(&agg[d.z], h[s.z] * w.z);
    atomicAdd(&agg[d.w], h[s.w] * w.w);
}
__global__ void fb_node_kernel(float* __restrict__ h, float* __restrict__ agg,
                               const int* __restrict__ gids, const float* __restrict__ Wn,
                               const float* __restrict__ bn, const float* __restrict__ Ws,
                               float* __restrict__ out, int l) {
    int i = blockIdx.x * blockDim.x + threadIdx.x;
    if (i >= N_NODES) return;
    float a = agg[i]; agg[i] = 0.0f;
    float hv = h[i];
    float hn = fmaxf(fmaf(a, Wn[l], fmaf(hv, Ws[l], bn[l])), 0.0f);
    h[i] = hn;
    seg_accum(gids[i], hn, out, l + 1);
}

// -----------------------------------------------------------------------------

extern "C" void kernel_launch(void* const* d_in, const int* in_sizes, int n_in,
                              void* d_out, int out_size, void* d_ws, size_t ws_size,
                              hipStream_t stream) {
    const float* x   = (const float*)d_in[0];
    const int*   src = (const int*)  d_in[1];
    const int*   dst = (const int*)  d_in[2];
    const float* ew  = (const float*)d_in[3];
    const int*   gid = (const int*)  d_in[4];
    const float* Wn  = (const float*)d_in[5];
    const float* bn  = (const float*)d_in[6];
    const float* Ws  = (const float*)d_in[7];
    float* out = (float*)d_out;

    hipMemsetAsync(d_out, 0, (size_t)out_size * sizeof(float), stream);

    size_t need = (size_t)N_EDGES * 8                       // recs
                + (size_t)N_NODES * 4 * 2                   // h0, h1
                + (size_t)NBKT * KSPLIT * BKT_NODES * 4     // partials (16 MB)
                + (size_t)(NBKT_PAD * 3 + 16) * 4;

    if (ws_size < need) {
        // fallback: round-1 atomic path (needs 8 MB)
        float* h   = (float*)d_ws;
        float* agg = (float*)d_ws + N_NODES;
        const int BT = 256;
        const int nb = (N_NODES + BT - 1) / BT;
        const int eb = (N_EDGES / 4 + BT - 1) / BT;
        fb_init_kernel<<<nb, BT, 0, stream>>>(x, gid, h, agg, out);
        for (int l = 0; l < N_LAYERS; ++l) {
            fb_edge_kernel<<<eb, BT, 0, stream>>>(
                (const int4*)src, (const int4*)dst, (const float4*)ew, h, agg);
            fb_node_kernel<<<nb, BT, 0, stream>>>(h, agg, gid, Wn, bn, Ws, out, l);
        }
        return;
    }

    char* p = (char*)d_ws;
    unsigned long long* recs = (unsigned long long*)p;  p += (size_t)N_EDGES * 8;
    float*    h0       = (float*)p;                     p += (size_t)N_NODES * 4;
    float*    h1       = (float*)p;                     p += (size_t)N_NODES * 4;
    float*    partials = (float*)p;                     p += (size_t)NBKT * KSPLIT * BKT_NODES * 4;
    unsigned* g_count  = (unsigned*)p;                  p += NBKT_PAD * 4;
    unsigned* g_cursor = (unsigned*)p;                  p += NBKT_PAD * 4;
    unsigned* g_base   = (unsigned*)p;                  p += (NBKT_PAD + 1) * 4;

    // zero counters (g_count and g_cursor are adjacent)
    hipMemsetAsync(g_count, 0, NBKT_PAD * 2 * sizeof(unsigned), stream);

    // binning (once per call, amortized over 8 layers)
    count_kernel  <<<2048, 256, 0, stream>>>((const int4*)dst, g_count);
    scan_kernel   <<<1, NBKT_PAD, 0, stream>>>(g_count, g_base, g_cursor);
    scatter_kernel<<<SCAT_BLOCKS, SCAT_THREADS, 0, stream>>>(src, dst, ew, g_cursor, recs);

    // forward
    const int BT = 256;
    const int nb = (N_NODES + BT - 1) / BT;
    init_kernel<<<nb, BT, 0, stream>>>(x, gid, h0, out);

    float* ha = h0;
    float* hb = h1;
    for (int l = 0; l < N_LAYERS; ++l) {
        edge_kernel<<<NBKT * KSPLIT, 512, 0, stream>>>(recs, g_base, ha, partials);
        node_kernel<<<nb, BT, 0, stream>>>(partials, ha, hb, gid, Wn, bn, Ws, out, l);
        float* t = ha; ha = hb; hb = t;
    }
}

// Round 6
// 2268.054 us; speedup vs baseline: 1.0616x; 1.0616x over previous
//
#include <hip/hip_runtime.h>

#define N_NODES  1000000
#define N_EDGES  32000000
#define N_GRAPHS 1024
#define N_LAYERS 8
#define OUT_COLS (N_LAYERS + 1)

#define BKT_SHIFT 11
#define BKT_NODES 2048
#define NBKT      489            // ceil(1e6 / 2048)
#define NBKT_PAD  512
#define SCAT_BLOCKS 256
#define SCAT_THREADS 1024
#define SCAT_CHUNK  (N_EDGES / SCAT_BLOCKS)   // 125000 exactly

// ---------------------------------------------------------------------------
// Wave-segmented accumulation of per-graph sums (graph_ids sorted, so most
// 64-lane waves are gid-uniform -> one atomic per wave). Call sites guarantee
// waves are fully active or fully inactive.
// ---------------------------------------------------------------------------
__device__ inline void seg_accum(int gid, float val, float* __restrict__ out, int col) {
    int g0 = __shfl(gid, 0);
    if (__all(gid == g0)) {
        #pragma unroll
        for (int off = 32; off > 0; off >>= 1)
            val += __shfl_down(val, off);
        if ((threadIdx.x & 63) == 0)
            atomicAdd(&out[g0 * OUT_COLS + col], val);
    } else {
        atomicAdd(&out[gid * OUT_COLS + col], val);
    }
}

// ------------------------- preprocessing: binning --------------------------

// P1: global bucket histogram (LDS-privatized, int4-vectorized)
__global__ void count_kernel(const int4* __restrict__ dst4, unsigned* __restrict__ g_count) {
    __shared__ unsigned hist[NBKT_PAD];
    for (int j = threadIdx.x; j < NBKT_PAD; j += blockDim.x) hist[j] = 0u;
    __syncthreads();
    int stride = gridDim.x * blockDim.x;
    for (int t = blockIdx.x * blockDim.x + threadIdx.x; t < N_EDGES / 4; t += stride) {
        int4 d = dst4[t];
        atomicAdd(&hist[((unsigned)d.x) >> BKT_SHIFT], 1u);
        atomicAdd(&hist[((unsigned)d.y) >> BKT_SHIFT], 1u);
        atomicAdd(&hist[((unsigned)d.z) >> BKT_SHIFT], 1u);
        atomicAdd(&hist[((unsigned)d.w) >> BKT_SHIFT], 1u);
    }
    __syncthreads();
    for (int j = threadIdx.x; j < NBKT_PAD; j += blockDim.x)
        if (hist[j]) atomicAdd(&g_count[j], hist[j]);
}

// P2: exclusive scan of padded bucket counts (single block of NBKT_PAD threads)
__global__ void scan_kernel(const unsigned* __restrict__ g_count,
                            unsigned* __restrict__ g_base,
                            unsigned* __restrict__ g_cursor) {
    __shared__ unsigned s[NBKT_PAD];
    int t = threadIdx.x;
    unsigned c = g_count[t];
    s[t] = c;
    __syncthreads();
    for (int off = 1; off < NBKT_PAD; off <<= 1) {
        unsigned v = (t >= off) ? s[t - off] : 0u;
        __syncthreads();
        s[t] += v;
        __syncthreads();
    }
    unsigned incl = s[t];
    g_base[t]   = incl - c;
    g_cursor[t] = incl - c;
    if (t == NBKT_PAD - 1) g_base[NBKT_PAD] = incl;
}

// P3: MSB pass — scatter edges into bucket-contiguous u64 records.
// rec = (src | dst_low11 << 20) << 32 | f32bits(weight)
__global__ void scatter_kernel(const int* __restrict__ src,
                               const int* __restrict__ dst,
                               const float* __restrict__ ew,
                               unsigned* __restrict__ g_cursor,
                               unsigned long long* __restrict__ recs) {
    __shared__ unsigned lhist[NBKT_PAD];
    __shared__ unsigned lbase[NBKT_PAD];
    int e0 = blockIdx.x * SCAT_CHUNK;
    int e1 = e0 + SCAT_CHUNK;
    for (int j = threadIdx.x; j < NBKT_PAD; j += blockDim.x) lhist[j] = 0u;
    __syncthreads();
    for (int e = e0 + threadIdx.x; e < e1; e += blockDim.x)
        atomicAdd(&lhist[((unsigned)dst[e]) >> BKT_SHIFT], 1u);
    __syncthreads();
    for (int j = threadIdx.x; j < NBKT_PAD; j += blockDim.x) {
        unsigned c = lhist[j];
        lbase[j] = c ? atomicAdd(&g_cursor[j], c) : 0u;
    }
    __syncthreads();
    for (int j = threadIdx.x; j < NBKT_PAD; j += blockDim.x) lhist[j] = 0u;  // reuse as cursor
    __syncthreads();
    for (int e = e0 + threadIdx.x; e < e1; e += blockDim.x) {
        unsigned d = (unsigned)dst[e];
        unsigned b = d >> BKT_SHIFT;
        unsigned loc = atomicAdd(&lhist[b], 1u);
        unsigned pos = lbase[b] + loc;
        unsigned hi  = ((unsigned)src[e]) | ((d & (BKT_NODES - 1u)) << 20);
        recs[pos] = ((unsigned long long)hi << 32) | (unsigned)__float_as_uint(ew[e]);
    }
}

// P4: LSB pass — per bucket, sort records by dst_low11 (counting sort) and
// emit row_ptr. Writes land in the bucket's ~524KB window (L2-merged).
__global__ __launch_bounds__(1024) void sort_kernel(
        const unsigned long long* __restrict__ recs_in,
        const unsigned* __restrict__ g_base,
        unsigned long long* __restrict__ recs_out,
        unsigned* __restrict__ row_ptr) {
    __shared__ unsigned cnt[BKT_NODES];   // 8 KB
    __shared__ unsigned ps[1024];         // 4 KB
    int b = blockIdx.x;
    int t = threadIdx.x;
    int e0 = (int)g_base[b];
    int e1 = (int)g_base[b + 1];
    cnt[t] = 0u; cnt[t + 1024] = 0u;
    __syncthreads();
    for (int e = e0 + t; e < e1; e += 1024)
        atomicAdd(&cnt[(unsigned)(recs_in[e] >> 52)], 1u);
    __syncthreads();
    unsigned c0 = cnt[2 * t], c1 = cnt[2 * t + 1];
    ps[t] = c0 + c1;
    __syncthreads();
    for (int off = 1; off < 1024; off <<= 1) {
        unsigned u = (t >= off) ? ps[t - off] : 0u;
        __syncthreads();
        ps[t] += u;
        __syncthreads();
    }
    unsigned exPair = ps[t] - (c0 + c1);
    unsigned ex0 = exPair, ex1 = exPair + c0;
    int nbase = b << BKT_SHIFT;
    int n0 = nbase + 2 * t, n1 = n0 + 1;
    if (n0 <= N_NODES) row_ptr[n0] = (unsigned)e0 + ex0;
    if (n1 <= N_NODES) row_ptr[n1] = (unsigned)e0 + ex1;
    __syncthreads();
    cnt[2 * t] = ex0; cnt[2 * t + 1] = ex1;   // reuse as cursors
    __syncthreads();
    for (int e = e0 + t; e < e1; e += 1024) {
        unsigned long long r = recs_in[e];
        unsigned j = (unsigned)(r >> 52);
        unsigned pos = (unsigned)e0 + atomicAdd(&cnt[j], 1u);
        recs_out[pos] = r;
    }
}

// ------------------------------ forward pass --------------------------------

// h0 = x; out[:,0] += per-graph sum of x
__global__ void init_kernel(const float* __restrict__ x,
                            const int* __restrict__ gids,
                            float* __restrict__ h0,
                            float* __restrict__ out) {
    int i = blockIdx.x * blockDim.x + threadIdx.x;
    if (i >= N_NODES) return;
    float v = x[i];
    h0[i] = v;
    seg_accum(gids[i], v, out, 0);
}

// CSR layer: one thread per node, serial accumulate of its contiguous edge
// run (plain loads: L1 catches the 8-records-per-line reuse; NO nontemporal
// here), then fused affine+relu + h write + per-graph sum. Zero atomics on
// the aggregation path.
__global__ __launch_bounds__(256) void layer_kernel(
        const unsigned long long* __restrict__ recs,
        const unsigned* __restrict__ row_ptr,
        const float* __restrict__ h_old,
        float* __restrict__ h_new,
        const int* __restrict__ gids,
        const float* __restrict__ Wn,
        const float* __restrict__ bn,
        const float* __restrict__ Ws,
        float* __restrict__ out,
        int l) {
    int n = blockIdx.x * 256 + threadIdx.x;
    if (n >= N_NODES) return;               // wave-uniform exit (N_NODES%64==0)
    int s = (int)row_ptr[n];
    int e = (int)row_ptr[n + 1];
    float a0 = 0.0f, a1 = 0.0f;
    int i = s;
    for (; i + 2 <= e; i += 2) {
        unsigned long long r0 = recs[i];
        unsigned long long r1 = recs[i + 1];
        a0 = fmaf(h_old[(unsigned)(r0 >> 32) & 0xFFFFFu], __uint_as_float((unsigned)r0), a0);
        a1 = fmaf(h_old[(unsigned)(r1 >> 32) & 0xFFFFFu], __uint_as_float((unsigned)r1), a1);
    }
    if (i < e) {
        unsigned long long r0 = recs[i];
        a0 = fmaf(h_old[(unsigned)(r0 >> 32) & 0xFFFFFu], __uint_as_float((unsigned)r0), a0);
    }
    float a = a0 + a1;
    float hn = fmaxf(fmaf(a, Wn[l], fmaf(h_old[n], Ws[l], bn[l])), 0.0f);
    h_new[n] = hn;
    seg_accum(gids[n], hn, out, l + 1);
}

// --------------------- tier-2 fallback (round-4 path) -----------------------

__global__ void bkt_layer_kernel(const unsigned long long* __restrict__ recs,
                                 const unsigned* __restrict__ g_base,
                                 const float* __restrict__ h_old,
                                 float* __restrict__ h_new,
                                 const int* __restrict__ gids,
                                 const float* __restrict__ Wn,
                                 const float* __restrict__ bn,
                                 const float* __restrict__ Ws,
                                 float* __restrict__ out,
                                 int l) {
    __shared__ float agg[BKT_NODES];
    int b = blockIdx.x;
    for (int j = threadIdx.x; j < BKT_NODES; j += blockDim.x) agg[j] = 0.0f;
    __syncthreads();
    int e0 = (int)g_base[b];
    int e1 = (int)g_base[b + 1];
    for (int e = e0 + threadIdx.x; e < e1; e += blockDim.x) {
        unsigned long long rec = __builtin_nontemporal_load(&recs[e]);
        unsigned hi = (unsigned)(rec >> 32);
        float w  = __uint_as_float((unsigned)rec);
        float hv = h_old[hi & 0xFFFFFu];
        atomicAdd(&agg[hi >> 20], hv * w);
    }
    __syncthreads();
    float wn = Wn[l], bb = bn[l], ws = Ws[l];
    int nbase = b << BKT_SHIFT;
    for (int j = threadIdx.x; j < BKT_NODES; j += blockDim.x) {
        int n = nbase + j;
        if (n < N_NODES) {
            float hn = fmaxf(fmaf(agg[j], wn, fmaf(h_old[n], ws, bb)), 0.0f);
            h_new[n] = hn;
            seg_accum(gids[n], hn, out, l + 1);
        }
    }
}

// --------------------- tier-3 fallback (round-1 path) -----------------------

__global__ void fb_init_kernel(const float* __restrict__ x, const int* __restrict__ gids,
                               float* __restrict__ h, float* __restrict__ agg,
                               float* __restrict__ out) {
    int i = blockIdx.x * blockDim.x + threadIdx.x;
    if (i >= N_NODES) return;
    float v = x[i];
    h[i] = v; agg[i] = 0.0f;
    seg_accum(gids[i], v, out, 0);
}
__global__ void fb_edge_kernel(const int4* __restrict__ src4, const int4* __restrict__ dst4,
                               const float4* __restrict__ ew4, const float* __restrict__ h,
                               float* __restrict__ agg) {
    int t = blockIdx.x * blockDim.x + threadIdx.x;
    if (t >= N_EDGES / 4) return;
    int4 s = src4[t]; int4 d = dst4[t]; float4 w = ew4[t];
    atomicAdd(&agg[d.x], h[s.x] * w.x);
    atomicAdd(&agg[d.y], h[s.y] * w.y);
    atomicAdd(&agg[d.z], h[s.z] * w.z);
    atomicAdd(&agg[d.w], h[s.w] * w.w);
}
__global__ void fb_node_kernel(float* __restrict__ h, float* __restrict__ agg,
                               const int* __restrict__ gids, const float* __restrict__ Wn,
                               const float* __restrict__ bn, const float* __restrict__ Ws,
                               float* __restrict__ out, int l) {
    int i = blockIdx.x * blockDim.x + threadIdx.x;
    if (i >= N_NODES) return;
    float a = agg[i]; agg[i] = 0.0f;
    float hv = h[i];
    float hn = fmaxf(fmaf(a, Wn[l], fmaf(hv, Ws[l], bn[l])), 0.0f);
    h[i] = hn;
    seg_accum(gids[i], hn, out, l + 1);
}

// -----------------------------------------------------------------------------

extern "C" void kernel_launch(void* const* d_in, const int* in_sizes, int n_in,
                              void* d_out, int out_size, void* d_ws, size_t ws_size,
                              hipStream_t stream) {
    const float* x   = (const float*)d_in[0];
    const int*   src = (const int*)  d_in[1];
    const int*   dst = (const int*)  d_in[2];
    const float* ew  = (const float*)d_in[3];
    const int*   gid = (const int*)  d_in[4];
    const float* Wn  = (const float*)d_in[5];
    const float* bn  = (const float*)d_in[6];
    const float* Ws  = (const float*)d_in[7];
    float* out = (float*)d_out;

    hipMemsetAsync(d_out, 0, (size_t)out_size * sizeof(float), stream);

    const int BT = 256;
    const int nb = (N_NODES + BT - 1) / BT;

    size_t need1 = (size_t)N_EDGES * 8 * 2                  // recs_tmp + recs
                 + (size_t)(N_NODES + 2) * 4                // row_ptr
                 + (size_t)N_NODES * 4 * 2                  // h0, h1
                 + (size_t)(NBKT_PAD * 3 + 16) * 4;
    size_t need2 = (size_t)N_EDGES * 8
                 + (size_t)N_NODES * 4 * 2
                 + (size_t)(NBKT_PAD * 3 + 16) * 4;

    if (ws_size >= need1) {
        char* p = (char*)d_ws;
        unsigned long long* recs_tmp = (unsigned long long*)p;  p += (size_t)N_EDGES * 8;
        unsigned long long* recs     = (unsigned long long*)p;  p += (size_t)N_EDGES * 8;
        unsigned* row_ptr  = (unsigned*)p;                      p += (size_t)(N_NODES + 2) * 4;
        float*    h0       = (float*)p;                         p += (size_t)N_NODES * 4;
        float*    h1       = (float*)p;                         p += (size_t)N_NODES * 4;
        unsigned* g_count  = (unsigned*)p;                      p += NBKT_PAD * 4;
        unsigned* g_cursor = (unsigned*)p;                      p += NBKT_PAD * 4;
        unsigned* g_base   = (unsigned*)p;                      p += (NBKT_PAD + 1) * 4;

        hipMemsetAsync(g_count, 0, NBKT_PAD * 2 * sizeof(unsigned), stream);

        count_kernel  <<<2048, 256, 0, stream>>>((const int4*)dst, g_count);
        scan_kernel   <<<1, NBKT_PAD, 0, stream>>>(g_count, g_base, g_cursor);
        scatter_kernel<<<SCAT_BLOCKS, SCAT_THREADS, 0, stream>>>(src, dst, ew, g_cursor, recs_tmp);
        sort_kernel   <<<NBKT, 1024, 0, stream>>>(recs_tmp, g_base, recs, row_ptr);

        init_kernel<<<nb, BT, 0, stream>>>(x, gid, h0, out);

        float* ha = h0;
        float* hb = h1;
        for (int l = 0; l < N_LAYERS; ++l) {
            layer_kernel<<<nb, BT, 0, stream>>>(recs, row_ptr, ha, hb,
                                                gid, Wn, bn, Ws, out, l);
            float* t = ha; ha = hb; hb = t;
        }
        return;
    }

    if (ws_size >= need2) {
        char* p = (char*)d_ws;
        unsigned long long* recs = (unsigned long long*)p;  p += (size_t)N_EDGES * 8;
        float*    h0       = (float*)p;                     p += (size_t)N_NODES * 4;
        float*    h1       = (float*)p;                     p += (size_t)N_NODES * 4;
        unsigned* g_count  = (unsigned*)p;                  p += NBKT_PAD * 4;
        unsigned* g_cursor = (unsigned*)p;                  p += NBKT_PAD * 4;
        unsigned* g_base   = (unsigned*)p;                  p += (NBKT_PAD + 1) * 4;

        hipMemsetAsync(g_count, 0, NBKT_PAD * 2 * sizeof(unsigned), stream);

        count_kernel  <<<2048, 256, 0, stream>>>((const int4*)dst, g_count);
        scan_kernel   <<<1, NBKT_PAD, 0, stream>>>(g_count, g_base, g_cursor);
        scatter_kernel<<<SCAT_BLOCKS, SCAT_THREADS, 0, stream>>>(src, dst, ew, g_cursor, recs);

        init_kernel<<<nb, BT, 0, stream>>>(x, gid, h0, out);

        float* ha = h0;
        float* hb = h1;
        for (int l = 0; l < N_LAYERS; ++l) {
            bkt_layer_kernel<<<NBKT, 512, 0, stream>>>(recs, g_base, ha, hb,
                                                       gid, Wn, bn, Ws, out, l);
            float* t = ha; ha = hb; hb = t;
        }
        return;
    }

    // tier-3: round-1 atomic path (needs 8 MB)
    float* h   = (float*)d_ws;
    float* agg = (float*)d_ws + N_NODES;
    const int eb = (N_EDGES / 4 + BT - 1) / BT;
    fb_init_kernel<<<nb, BT, 0, stream>>>(x, gid, h, agg, out);
    for (int l = 0; l < N_LAYERS; ++l) {
        fb_edge_kernel<<<eb, BT, 0, stream>>>(
            (const int4*)src, (const int4*)dst, (const float4*)ew, h, agg);
        fb_node_kernel<<<nb, BT, 0, stream>>>(h, agg, gid, Wn, bn, Ws, out, l);
    }
}

// Round 7
// 2265.579 us; speedup vs baseline: 1.0628x; 1.0011x over previous
//
#include <hip/hip_runtime.h>

#define N_NODES  1000000
#define N_EDGES  32000000
#define N_GRAPHS 1024
#define N_LAYERS 8
#define OUT_COLS (N_LAYERS + 1)

#define BKT_SHIFT 11
#define BKT_NODES 2048
#define NBKT      489            // ceil(1e6 / 2048)
#define NBKT_PAD  512
#define SCAT_BLOCKS 256
#define SCAT_THREADS 1024
#define SCAT_CHUNK  (N_EDGES / SCAT_BLOCKS)   // 125000 exactly

#define NPB  128                 // nodes per block in layer kernel (2 waves)
#define CAP  4608                // LDS record capacity (36 KB); mean fill 4096

// ---------------------------------------------------------------------------
// Wave-segmented accumulation of per-graph sums (graph_ids sorted, so most
// 64-lane waves are gid-uniform -> one atomic per wave). Call sites guarantee
// waves are fully active or fully inactive.
// ---------------------------------------------------------------------------
__device__ inline void seg_accum(int gid, float val, float* __restrict__ out, int col) {
    int g0 = __shfl(gid, 0);
    if (__all(gid == g0)) {
        #pragma unroll
        for (int off = 32; off > 0; off >>= 1)
            val += __shfl_down(val, off);
        if ((threadIdx.x & 63) == 0)
            atomicAdd(&out[g0 * OUT_COLS + col], val);
    } else {
        atomicAdd(&out[gid * OUT_COLS + col], val);
    }
}

// ------------------------- preprocessing: binning --------------------------

// P1: global bucket histogram (LDS-privatized x4 replication, int4-vectorized)
__global__ void count_kernel(const int4* __restrict__ dst4, unsigned* __restrict__ g_count) {
    __shared__ unsigned hist[NBKT_PAD * 4];
    for (int j = threadIdx.x; j < NBKT_PAD * 4; j += blockDim.x) hist[j] = 0u;
    __syncthreads();
    int rep = threadIdx.x & 3;
    int stride = gridDim.x * blockDim.x;
    for (int t = blockIdx.x * blockDim.x + threadIdx.x; t < N_EDGES / 4; t += stride) {
        int4 d = dst4[t];
        atomicAdd(&hist[((((unsigned)d.x) >> BKT_SHIFT) << 2) + rep], 1u);
        atomicAdd(&hist[((((unsigned)d.y) >> BKT_SHIFT) << 2) + rep], 1u);
        atomicAdd(&hist[((((unsigned)d.z) >> BKT_SHIFT) << 2) + rep], 1u);
        atomicAdd(&hist[((((unsigned)d.w) >> BKT_SHIFT) << 2) + rep], 1u);
    }
    __syncthreads();
    for (int j = threadIdx.x; j < NBKT_PAD; j += blockDim.x) {
        unsigned s = hist[4*j] + hist[4*j+1] + hist[4*j+2] + hist[4*j+3];
        if (s) atomicAdd(&g_count[j], s);
    }
}

// P2: exclusive scan of padded bucket counts (single block of NBKT_PAD threads)
__global__ void scan_kernel(const unsigned* __restrict__ g_count,
                            unsigned* __restrict__ g_base,
                            unsigned* __restrict__ g_cursor) {
    __shared__ unsigned s[NBKT_PAD];
    int t = threadIdx.x;
    unsigned c = g_count[t];
    s[t] = c;
    __syncthreads();
    for (int off = 1; off < NBKT_PAD; off <<= 1) {
        unsigned v = (t >= off) ? s[t - off] : 0u;
        __syncthreads();
        s[t] += v;
        __syncthreads();
    }
    unsigned incl = s[t];
    g_base[t]   = incl - c;
    g_cursor[t] = incl - c;
    if (t == NBKT_PAD - 1) g_base[NBKT_PAD] = incl;
}

// P3: MSB pass — scatter edges into bucket-contiguous u64 records.
// rec = (src | dst_low11 << 20) << 32 | f32bits(weight)
__global__ void scatter_kernel(const int* __restrict__ src,
                               const int* __restrict__ dst,
                               const float* __restrict__ ew,
                               unsigned* __restrict__ g_cursor,
                               unsigned long long* __restrict__ recs) {
    __shared__ unsigned lhist[NBKT_PAD];
    __shared__ unsigned lbase[NBKT_PAD];
    int e0 = blockIdx.x * SCAT_CHUNK;
    int e1 = e0 + SCAT_CHUNK;
    for (int j = threadIdx.x; j < NBKT_PAD; j += blockDim.x) lhist[j] = 0u;
    __syncthreads();
    for (int e = e0 + threadIdx.x; e < e1; e += blockDim.x)
        atomicAdd(&lhist[((unsigned)dst[e]) >> BKT_SHIFT], 1u);
    __syncthreads();
    for (int j = threadIdx.x; j < NBKT_PAD; j += blockDim.x) {
        unsigned c = lhist[j];
        lbase[j] = c ? atomicAdd(&g_cursor[j], c) : 0u;
    }
    __syncthreads();
    for (int j = threadIdx.x; j < NBKT_PAD; j += blockDim.x) lhist[j] = 0u;  // reuse as cursor
    __syncthreads();
    for (int e = e0 + threadIdx.x; e < e1; e += blockDim.x) {
        unsigned d = (unsigned)dst[e];
        unsigned b = d >> BKT_SHIFT;
        unsigned loc = atomicAdd(&lhist[b], 1u);
        unsigned pos = lbase[b] + loc;
        unsigned hi  = ((unsigned)src[e]) | ((d & (BKT_NODES - 1u)) << 20);
        recs[pos] = ((unsigned long long)hi << 32) | (unsigned)__float_as_uint(ew[e]);
    }
}

// P4: LSB pass — per bucket, sort records by dst_low11 (counting sort) and
// emit row_ptr. Writes land in the bucket's ~524KB window (L2-merged).
__global__ __launch_bounds__(1024) void sort_kernel(
        const unsigned long long* __restrict__ recs_in,
        const unsigned* __restrict__ g_base,
        unsigned long long* __restrict__ recs_out,
        unsigned* __restrict__ row_ptr) {
    __shared__ unsigned cnt[BKT_NODES];   // 8 KB
    __shared__ unsigned ps[1024];         // 4 KB
    int b = blockIdx.x;
    int t = threadIdx.x;
    int e0 = (int)g_base[b];
    int e1 = (int)g_base[b + 1];
    cnt[t] = 0u; cnt[t + 1024] = 0u;
    __syncthreads();
    for (int e = e0 + t; e < e1; e += 1024)
        atomicAdd(&cnt[(unsigned)(recs_in[e] >> 52)], 1u);
    __syncthreads();
    unsigned c0 = cnt[2 * t], c1 = cnt[2 * t + 1];
    ps[t] = c0 + c1;
    __syncthreads();
    for (int off = 1; off < 1024; off <<= 1) {
        unsigned u = (t >= off) ? ps[t - off] : 0u;
        __syncthreads();
        ps[t] += u;
        __syncthreads();
    }
    unsigned exPair = ps[t] - (c0 + c1);
    unsigned ex0 = exPair, ex1 = exPair + c0;
    int nbase = b << BKT_SHIFT;
    int n0 = nbase + 2 * t, n1 = n0 + 1;
    if (n0 <= N_NODES) row_ptr[n0] = (unsigned)e0 + ex0;
    if (n1 <= N_NODES) row_ptr[n1] = (unsigned)e0 + ex1;
    __syncthreads();
    cnt[2 * t] = ex0; cnt[2 * t + 1] = ex1;   // reuse as cursors
    __syncthreads();
    for (int e = e0 + t; e < e1; e += 1024) {
        unsigned long long r = recs_in[e];
        unsigned j = (unsigned)(r >> 52);
        unsigned pos = (unsigned)e0 + atomicAdd(&cnt[j], 1u);
        recs_out[pos] = r;
    }
}

// ------------------------------ forward pass --------------------------------

// h0 = x; out[:,0] += per-graph sum of x
__global__ void init_kernel(const float* __restrict__ x,
                            const int* __restrict__ gids,
                            float* __restrict__ h0,
                            float* __restrict__ out) {
    int i = blockIdx.x * blockDim.x + threadIdx.x;
    if (i >= N_NODES) return;
    float v = x[i];
    h0[i] = v;
    seg_accum(gids[i], v, out, 0);
}

// CSR layer, LDS-staged: one block = 128 nodes = one contiguous record range.
// Records are streamed into LDS with NONTEMPORAL coalesced loads (they bypass
// L2, so h_old stays L2-resident for the 32M random gathers). row_ptr/gids
// reads and the h_new store are nontemporal too; h_old is the only L2-warm
// array. Chunk loop handles any block whose range exceeds CAP.
__global__ __launch_bounds__(NPB) void layer_kernel(
        const unsigned long long* __restrict__ recs,
        const unsigned* __restrict__ row_ptr,
        const float* __restrict__ h_old,
        float* __restrict__ h_new,
        const int* __restrict__ gids,
        const float* __restrict__ Wn,
        const float* __restrict__ bn,
        const float* __restrict__ Ws,
        float* __restrict__ out,
        int l) {
    __shared__ unsigned long long lds[CAP];   // 36 KB -> 4 blocks/CU
    int t = threadIdx.x;
    int nb0 = blockIdx.x * NPB;
    int nend = nb0 + NPB; if (nend > N_NODES) nend = N_NODES;
    int blk_e0 = (int)__builtin_nontemporal_load(&row_ptr[nb0]);
    int blk_e1 = (int)__builtin_nontemporal_load(&row_ptr[nend]);
    int n = nb0 + t;
    int s = blk_e1, e = blk_e1;               // inactive threads: empty run
    if (n < N_NODES) {
        s = (int)__builtin_nontemporal_load(&row_ptr[n]);
        e = (int)__builtin_nontemporal_load(&row_ptr[n + 1]);
    }
    float a0 = 0.0f, a1 = 0.0f;
    for (int c0 = blk_e0; c0 < blk_e1; c0 += CAP) {
        int c1 = c0 + CAP; if (c1 > blk_e1) c1 = blk_e1;
        __syncthreads();                       // protect LDS reuse across chunks
        for (int i = c0 + t; i < c1; i += NPB)
            lds[i - c0] = __builtin_nontemporal_load(&recs[i]);
        __syncthreads();
        int ls = s > c0 ? s : c0;
        int le = e < c1 ? e : c1;
        int i = ls;
        for (; i + 2 <= le; i += 2) {
            unsigned long long r0 = lds[i - c0];
            unsigned long long r1 = lds[i + 1 - c0];
            a0 = fmaf(h_old[(unsigned)(r0 >> 32) & 0xFFFFFu], __uint_as_float((unsigned)r0), a0);
            a1 = fmaf(h_old[(unsigned)(r1 >> 32) & 0xFFFFFu], __uint_as_float((unsigned)r1), a1);
        }
        if (i < le) {
            unsigned long long r0 = lds[i - c0];
            a0 = fmaf(h_old[(unsigned)(r0 >> 32) & 0xFFFFFu], __uint_as_float((unsigned)r0), a0);
        }
    }
    if (n < N_NODES) {                         // whole waves skip (64-aligned)
        float hn = fmaxf(fmaf(a0 + a1, Wn[l], fmaf(h_old[n], Ws[l], bn[l])), 0.0f);
        __builtin_nontemporal_store(hn, &h_new[n]);
        int g = __builtin_nontemporal_load(&gids[n]);
        seg_accum(g, hn, out, l + 1);
    }
}

// --------------------- tier-2 fallback (round-4 path) -----------------------

__global__ void bkt_layer_kernel(const unsigned long long* __restrict__ recs,
                                 const unsigned* __restrict__ g_base,
                                 const float* __restrict__ h_old,
                                 float* __restrict__ h_new,
                                 const int* __restrict__ gids,
                                 const float* __restrict__ Wn,
                                 const float* __restrict__ bn,
                                 const float* __restrict__ Ws,
                                 float* __restrict__ out,
                                 int l) {
    __shared__ float agg[BKT_NODES];
    int b = blockIdx.x;
    for (int j = threadIdx.x; j < BKT_NODES; j += blockDim.x) agg[j] = 0.0f;
    __syncthreads();
    int e0 = (int)g_base[b];
    int e1 = (int)g_base[b + 1];
    for (int e = e0 + threadIdx.x; e < e1; e += blockDim.x) {
        unsigned long long rec = __builtin_nontemporal_load(&recs[e]);
        unsigned hi = (unsigned)(rec >> 32);
        float w  = __uint_as_float((unsigned)rec);
        float hv = h_old[hi & 0xFFFFFu];
        atomicAdd(&agg[hi >> 20], hv * w);
    }
    __syncthreads();
    float wn = Wn[l], bb = bn[l], ws = Ws[l];
    int nbase = b << BKT_SHIFT;
    for (int j = threadIdx.x; j < BKT_NODES; j += blockDim.x) {
        int n = nbase + j;
        if (n < N_NODES) {
            float hn = fmaxf(fmaf(agg[j], wn, fmaf(h_old[n], ws, bb)), 0.0f);
            h_new[n] = hn;
            seg_accum(gids[n], hn, out, l + 1);
        }
    }
}

// --------------------- tier-3 fallback (round-1 path) -----------------------

__global__ void fb_init_kernel(const float* __restrict__ x, const int* __restrict__ gids,
                               float* __restrict__ h, float* __restrict__ agg,
                               float* __restrict__ out) {
    int i = blockIdx.x * blockDim.x + threadIdx.x;
    if (i >= N_NODES) return;
    float v = x[i];
    h[i] = v; agg[i] = 0.0f;
    seg_accum(gids[i], v, out, 0);
}
__global__ void fb_edge_kernel(const int4* __restrict__ src4, const int4* __restrict__ dst4,
                               const float4* __restrict__ ew4, const float* __restrict__ h,
                               float* __restrict__ agg) {
    int t = blockIdx.x * blockDim.x + threadIdx.x;
    if (t >= N_EDGES / 4) return;
    int4 s = src4[t]; int4 d = dst4[t]; float4 w = ew4[t];
    atomicAdd(&agg[d.x], h[s.x] * w.x);
    atomicAdd(&agg[d.y], h[s.y] * w.y);
    atomicAdd(&agg[d.z], h[s.z] * w.z);
    atomicAdd(&agg[d.w], h[s.w] * w.w);
}
__global__ void fb_node_kernel(float* __restrict__ h, float* __restrict__ agg,
                               const int* __restrict__ gids, const float* __restrict__ Wn,
                               const float* __restrict__ bn, const float* __restrict__ Ws,
                               float* __restrict__ out, int l) {
    int i = blockIdx.x * blockDim.x + threadIdx.x;
    if (i >= N_NODES) return;
    float a = agg[i]; agg[i] = 0.0f;
    float hv = h[i];
    float hn = fmaxf(fmaf(a, Wn[l], fmaf(hv, Ws[l], bn[l])), 0.0f);
    h[i] = hn;
    seg_accum(gids[i], hn, out, l + 1);
}

// -----------------------------------------------------------------------------

extern "C" void kernel_launch(void* const* d_in, const int* in_sizes, int n_in,
                              void* d_out, int out_size, void* d_ws, size_t ws_size,
                              hipStream_t stream) {
    const float* x   = (const float*)d_in[0];
    const int*   src = (const int*)  d_in[1];
    const int*   dst = (const int*)  d_in[2];
    const float* ew  = (const float*)d_in[3];
    const int*   gid = (const int*)  d_in[4];
    const float* Wn  = (const float*)d_in[5];
    const float* bn  = (const float*)d_in[6];
    const float* Ws  = (const float*)d_in[7];
    float* out = (float*)d_out;

    hipMemsetAsync(d_out, 0, (size_t)out_size * sizeof(float), stream);

    const int BT = 256;
    const int nb = (N_NODES + BT - 1) / BT;

    size_t need1 = (size_t)N_EDGES * 8 * 2                  // recs_tmp + recs
                 + (size_t)(N_NODES + 2) * 4                // row_ptr
                 + (size_t)N_NODES * 4 * 2                  // h0, h1
                 + (size_t)(NBKT_PAD * 3 + 16) * 4;
    size_t need2 = (size_t)N_EDGES * 8
                 + (size_t)N_NODES * 4 * 2
                 + (size_t)(NBKT_PAD * 3 + 16) * 4;

    if (ws_size >= need1) {
        char* p = (char*)d_ws;
        unsigned long long* recs_tmp = (unsigned long long*)p;  p += (size_t)N_EDGES * 8;
        unsigned long long* recs     = (unsigned long long*)p;  p += (size_t)N_EDGES * 8;
        unsigned* row_ptr  = (unsigned*)p;                      p += (size_t)(N_NODES + 2) * 4;
        float*    h0       = (float*)p;                         p += (size_t)N_NODES * 4;
        float*    h1       = (float*)p;                         p += (size_t)N_NODES * 4;
        unsigned* g_count  = (unsigned*)p;                      p += NBKT_PAD * 4;
        unsigned* g_cursor = (unsigned*)p;                      p += NBKT_PAD * 4;
        unsigned* g_base   = (unsigned*)p;                      p += (NBKT_PAD + 1) * 4;

        hipMemsetAsync(g_count, 0, NBKT_PAD * 2 * sizeof(unsigned), stream);

        count_kernel  <<<2048, 256, 0, stream>>>((const int4*)dst, g_count);
        scan_kernel   <<<1, NBKT_PAD, 0, stream>>>(g_count, g_base, g_cursor);
        scatter_kernel<<<SCAT_BLOCKS, SCAT_THREADS, 0, stream>>>(src, dst, ew, g_cursor, recs_tmp);
        sort_kernel   <<<NBKT, 1024, 0, stream>>>(recs_tmp, g_base, recs, row_ptr);

        init_kernel<<<nb, BT, 0, stream>>>(x, gid, h0, out);

        float* ha = h0;
        float* hb = h1;
        const int lb = (N_NODES + NPB - 1) / NPB;
        for (int l = 0; l < N_LAYERS; ++l) {
            layer_kernel<<<lb, NPB, 0, stream>>>(recs, row_ptr, ha, hb,
                                                 gid, Wn, bn, Ws, out, l);
            float* t = ha; ha = hb; hb = t;
        }
        return;
    }

    if (ws_size >= need2) {
        char* p = (char*)d_ws;
        unsigned long long* recs = (unsigned long long*)p;  p += (size_t)N_EDGES * 8;
        float*    h0       = (float*)p;                     p += (size_t)N_NODES * 4;
        float*    h1       = (float*)p;                     p += (size_t)N_NODES * 4;
        unsigned* g_count  = (unsigned*)p;                  p += NBKT_PAD * 4;
        unsigned* g_cursor = (unsigned*)p;                  p += NBKT_PAD * 4;
        unsigned* g_base   = (unsigned*)p;                  p += (NBKT_PAD + 1) * 4;

        hipMemsetAsync(g_count, 0, NBKT_PAD * 2 * sizeof(unsigned), stream);

        count_kernel  <<<2048, 256, 0, stream>>>((const int4*)dst, g_count);
        scan_kernel   <<<1, NBKT_PAD, 0, stream>>>(g_count, g_base, g_cursor);
        scatter_kernel<<<SCAT_BLOCKS, SCAT_THREADS, 0, stream>>>(src, dst, ew, g_cursor, recs);

        init_kernel<<<nb, BT, 0, stream>>>(x, gid, h0, out);

        float* ha = h0;
        float* hb = h1;
        for (int l = 0; l < N_LAYERS; ++l) {
            bkt_layer_kernel<<<NBKT, 512, 0, stream>>>(recs, g_base, ha, hb,
                                                       gid, Wn, bn, Ws, out, l);
            float* t = ha; ha = hb; hb = t;
        }
        return;
    }

    // tier-3: round-1 atomic path (needs 8 MB)
    float* h   = (float*)d_ws;
    float* agg = (float*)d_ws + N_NODES;
    const int eb = (N_EDGES / 4 + BT - 1) / BT;
    fb_init_kernel<<<nb, BT, 0, stream>>>(x, gid, h, agg, out);
    for (int l = 0; l < N_LAYERS; ++l) {
        fb_edge_kernel<<<eb, BT, 0, stream>>>(
            (const int4*)src, (const int4*)dst, (const float4*)ew, h, agg);
        fb_node_kernel<<<nb, BT, 0, stream>>>(h, agg, gid, Wn, bn, Ws, out, l);
    }
}